// Round 11
// baseline (142.883 us; speedup 1.0000x reference)
//
#include <hip/hip_runtime.h>

#define B_BATCH 16
#define XLEN    320000
#define NFFT    2048
#define HOP     512
#define PADW    1024
#define NFREQ   1025
#define T_OUT   626
#define M_ROWS  2050
#define NCOLS   (B_BATCH * T_OUT)          // 10016
#define MT3     9                           // ceil(2050/256) -> pad to 2304
#define NT3     79                          // ceil(10016/128)
#define NBLK3   (MT3 * NT3)                 // 711 = 8*88 + 7
#define KT2     32                          // 2048/64

#define XPAD_LEN    322048
#define XPAD_STRIDE 330240
#define APACK_BYTES ((size_t)MT3 * 32 * 2 * 16384)             // 9,437,184
#define XPAD_BYTES  ((size_t)(B_BATCH + 1) * XPAD_STRIDE * 2)  // 11,228,160 (slot 16 = zeros)
#define WS_NEEDED   (APACK_BYTES + XPAD_BYTES)

typedef __bf16 bf16x8 __attribute__((ext_vector_type(8)));
typedef __bf16 bf16x4 __attribute__((ext_vector_type(4)));
typedef float  f32x4  __attribute__((ext_vector_type(4)));

__device__ __forceinline__ void gload_lds16(const void* g, void* l) {
    __builtin_amdgcn_global_load_lds(
        (const __attribute__((address_space(1))) unsigned int*)g,
        (__attribute__((address_space(3))) unsigned int*)l,
        16, 0, 0);
}

// ---------------- prep A: weights fp32 -> bf16, [mt256][kt][half][row][cell] ----
// Half-tile (mt,kt,half) = 16 KB: byte row*128 + cell*16 holds
// W[mt*256+half*128+row][kt*64 + ((cell ^ (row&7))<<3) + e], e in [0,8).
__global__ __launch_bounds__(256) void prep_w(
    const float* __restrict__ wre, const float* __restrict__ wim,
    __bf16* __restrict__ apack)
{
    const int gid  = blockIdx.x * 256 + threadIdx.x;   // 589824 total
    const int cell = gid & 7;
    const int row  = (gid >> 3) & 127;
    const int half = (gid >> 10) & 1;
    const int kt   = (gid >> 11) & 31;
    const int mt   = gid >> 16;

    const int grow = mt * 256 + half * 128 + row;
    const int k    = kt * 64 + ((cell ^ (row & 7)) << 3);

    bf16x8 v = bf16x8{};
    if (grow < M_ROWS) {
        const float* src = (grow < NFREQ)
            ? (wre + (size_t)grow * NFFT + k)
            : (wim + (size_t)(grow - NFREQ) * NFFT + k);
        const float4 a = *reinterpret_cast<const float4*>(src);
        const float4 b = *reinterpret_cast<const float4*>(src + 4);
        v[0] = (__bf16)a.x; v[1] = (__bf16)a.y; v[2] = (__bf16)a.z; v[3] = (__bf16)a.w;
        v[4] = (__bf16)b.x; v[5] = (__bf16)b.y; v[6] = (__bf16)b.z; v[7] = (__bf16)b.w;
    }
    *reinterpret_cast<bf16x8*>(apack + (size_t)gid * 8) = v;
}

// ---------------- prep B: reflect-padded signal fp32 -> bf16 (slot 16 = zeros) ----
__global__ __launch_bounds__(256) void prep_x(
    const float* __restrict__ x, __bf16* __restrict__ xpad)
{
    const int gid = blockIdx.x * 256 + threadIdx.x;
    if (gid >= (B_BATCH + 1) * (XPAD_STRIDE / 8)) return;
    const int b  = gid / (XPAD_STRIDE / 8);
    const int i0 = (gid - b * (XPAD_STRIDE / 8)) * 8;

    bf16x8 v = bf16x8{};
    if (b < B_BATCH) {
        const float* xb = x + (size_t)b * XLEN;
        const int pos0 = i0 - PADW;
        if (pos0 >= 0 && pos0 + 8 <= XLEN) {
            const float4 a = *reinterpret_cast<const float4*>(xb + pos0);
            const float4 c = *reinterpret_cast<const float4*>(xb + pos0 + 4);
            v[0] = (__bf16)a.x; v[1] = (__bf16)a.y; v[2] = (__bf16)a.z; v[3] = (__bf16)a.w;
            v[4] = (__bf16)c.x; v[5] = (__bf16)c.y; v[6] = (__bf16)c.z; v[7] = (__bf16)c.w;
        } else {
            #pragma unroll
            for (int e = 0; e < 8; ++e) {
                const int i = i0 + e;
                if (i >= XPAD_LEN) { v[e] = (__bf16)0.f; continue; }
                int p = i - PADW;
                p = (p < 0) ? -p : p;
                p = (p >= XLEN) ? (2 * XLEN - 2 - p) : p;
                v[e] = (__bf16)xb[p];
            }
        }
    }
    *reinterpret_cast<bf16x8*>(xpad + (size_t)b * XPAD_STRIDE + i0) = v;
}

// ---------------- main GEMM: 256x128 tile, dual-barrier 2-phase/K-tile ----
// 512 thr = 8 waves (4M x 2N), per-wave 64x64. LDS = 2 buf x (A 32K + B 16K)
// = 96 KB -> 1 block/CU. Tile t (buf t&1): phA {12 ds_read (A m0-3 x kk0-1 +
// B n0-1), stage ALL of tile t+1 (6 gloads), barrier, lgkm0, 16 MFMA n0-1,
// barrier}; phB {4 ds_read (B n2-3), VM0 (stages in flight >= 1 full phase),
// barrier, lgkm0, 16 MFMA n2-3, barrier}. A-frags register-cached per tile.

#define MFMA16 __builtin_amdgcn_mfma_f32_16x16x32_bf16
#define VM0 asm volatile("s_waitcnt vmcnt(0)" ::: "memory");

#define STGT(KT_, BUF_) {                                                         \
    const char* as_ = ablk + (size_t)(KT_) * 32768;                               \
    unsigned char* ad_ = lds + (BUF_) + (wid << 10);                              \
    gload_lds16(as_,         ad_);                                                \
    gload_lds16(as_ + 8192,  ad_ + 8192);                                         \
    gload_lds16(as_ + 16384, ad_ + 16384);                                        \
    gload_lds16(as_ + 24576, ad_ + 24576);                                        \
    const int ko_ = (KT_) << 7;                                                   \
    gload_lds16(gb0 + ko_, lds + (BUF_) + 32768 + (wid << 10));                   \
    gload_lds16(gb1 + ko_, lds + (BUF_) + 40960 + (wid << 10));                   \
}

#define PHA(BUF_, STG_) {                                                         \
    a00 = *(const bf16x8*)(lds + (BUF_) + aoff0);                                 \
    a01 = *(const bf16x8*)(lds + (BUF_) + aoff1);                                 \
    a10 = *(const bf16x8*)(lds + (BUF_) + aoff0 + 2048);                          \
    a11 = *(const bf16x8*)(lds + (BUF_) + aoff1 + 2048);                          \
    a20 = *(const bf16x8*)(lds + (BUF_) + aoff0 + 4096);                          \
    a21 = *(const bf16x8*)(lds + (BUF_) + aoff1 + 4096);                          \
    a30 = *(const bf16x8*)(lds + (BUF_) + aoff0 + 6144);                          \
    a31 = *(const bf16x8*)(lds + (BUF_) + aoff1 + 6144);                          \
    bf16x8 b00 = *(const bf16x8*)(lds + (BUF_) + boff0);                          \
    bf16x8 b01 = *(const bf16x8*)(lds + (BUF_) + boff1);                          \
    bf16x8 b10 = *(const bf16x8*)(lds + (BUF_) + boff0 + 2048);                   \
    bf16x8 b11 = *(const bf16x8*)(lds + (BUF_) + boff1 + 2048);                   \
    STG_                                                                          \
    __builtin_amdgcn_s_barrier();                                                 \
    asm volatile("s_waitcnt lgkmcnt(0)" ::: "memory");                            \
    __builtin_amdgcn_sched_barrier(0);                                            \
    __builtin_amdgcn_s_setprio(1);                                                \
    acc[0][0] = MFMA16(a00, b00, acc[0][0], 0, 0, 0);                             \
    acc[0][0] = MFMA16(a01, b01, acc[0][0], 0, 0, 0);                             \
    acc[1][0] = MFMA16(a10, b00, acc[1][0], 0, 0, 0);                             \
    acc[1][0] = MFMA16(a11, b01, acc[1][0], 0, 0, 0);                             \
    acc[2][0] = MFMA16(a20, b00, acc[2][0], 0, 0, 0);                             \
    acc[2][0] = MFMA16(a21, b01, acc[2][0], 0, 0, 0);                             \
    acc[3][0] = MFMA16(a30, b00, acc[3][0], 0, 0, 0);                             \
    acc[3][0] = MFMA16(a31, b01, acc[3][0], 0, 0, 0);                             \
    acc[0][1] = MFMA16(a00, b10, acc[0][1], 0, 0, 0);                             \
    acc[0][1] = MFMA16(a01, b11, acc[0][1], 0, 0, 0);                             \
    acc[1][1] = MFMA16(a10, b10, acc[1][1], 0, 0, 0);                             \
    acc[1][1] = MFMA16(a11, b11, acc[1][1], 0, 0, 0);                             \
    acc[2][1] = MFMA16(a20, b10, acc[2][1], 0, 0, 0);                             \
    acc[2][1] = MFMA16(a21, b11, acc[2][1], 0, 0, 0);                             \
    acc[3][1] = MFMA16(a30, b10, acc[3][1], 0, 0, 0);                             \
    acc[3][1] = MFMA16(a31, b11, acc[3][1], 0, 0, 0);                             \
    __builtin_amdgcn_s_setprio(0);                                                \
    __builtin_amdgcn_s_barrier();                                                 \
}

#define PHB(BUF_, VMW_) {                                                         \
    bf16x8 b20 = *(const bf16x8*)(lds + (BUF_) + boff0 + 4096);                   \
    bf16x8 b21 = *(const bf16x8*)(lds + (BUF_) + boff1 + 4096);                   \
    bf16x8 b30 = *(const bf16x8*)(lds + (BUF_) + boff0 + 6144);                   \
    bf16x8 b31 = *(const bf16x8*)(lds + (BUF_) + boff1 + 6144);                   \
    VMW_                                                                          \
    __builtin_amdgcn_s_barrier();                                                 \
    asm volatile("s_waitcnt lgkmcnt(0)" ::: "memory");                            \
    __builtin_amdgcn_sched_barrier(0);                                            \
    __builtin_amdgcn_s_setprio(1);                                                \
    acc[0][2] = MFMA16(a00, b20, acc[0][2], 0, 0, 0);                             \
    acc[0][2] = MFMA16(a01, b21, acc[0][2], 0, 0, 0);                             \
    acc[1][2] = MFMA16(a10, b20, acc[1][2], 0, 0, 0);                             \
    acc[1][2] = MFMA16(a11, b21, acc[1][2], 0, 0, 0);                             \
    acc[2][2] = MFMA16(a20, b20, acc[2][2], 0, 0, 0);                             \
    acc[2][2] = MFMA16(a21, b21, acc[2][2], 0, 0, 0);                             \
    acc[3][2] = MFMA16(a30, b20, acc[3][2], 0, 0, 0);                             \
    acc[3][2] = MFMA16(a31, b21, acc[3][2], 0, 0, 0);                             \
    acc[0][3] = MFMA16(a00, b30, acc[0][3], 0, 0, 0);                             \
    acc[0][3] = MFMA16(a01, b31, acc[0][3], 0, 0, 0);                             \
    acc[1][3] = MFMA16(a10, b30, acc[1][3], 0, 0, 0);                             \
    acc[1][3] = MFMA16(a11, b31, acc[1][3], 0, 0, 0);                             \
    acc[2][3] = MFMA16(a20, b30, acc[2][3], 0, 0, 0);                             \
    acc[2][3] = MFMA16(a21, b31, acc[2][3], 0, 0, 0);                             \
    acc[3][3] = MFMA16(a30, b30, acc[3][3], 0, 0, 0);                             \
    acc[3][3] = MFMA16(a31, b31, acc[3][3], 0, 0, 0);                             \
    __builtin_amdgcn_s_setprio(0);                                                \
    __builtin_amdgcn_s_barrier();                                                 \
}

__global__ __launch_bounds__(512, 2) void stft_gemm11(
    const __bf16* __restrict__ apack,
    const __bf16* __restrict__ xpad,
    float* __restrict__ out)
{
    __shared__ __align__(16) unsigned char lds[98304];   // 2 x 48 KB -> 1 block/CU

    const int tid  = threadIdx.x;
    const int lane = tid & 63;
    const int wid  = tid >> 6;   // 0..7
    const int wm   = wid >> 1;   // 0..3 (64-row strip)
    const int wn   = wid & 1;    // 0..1 (64-col strip)
    const int fr   = lane & 15;
    const int kq   = lane >> 4;

    // bijective XCD-chunked swizzle: 711 = 8*88 + 7 (residues 0..6 -> 89 each)
    int G;
    {
        const int L = blockIdx.x;
        const int xcd = L & 7;
        const int pos = L >> 3;
        G = (xcd < 7) ? xcd * 89 + pos : 623 + pos;
    }
    const int mt = G / NT3;
    const int nt = G - mt * NT3;

    // ---- staging bases
    const char* ablk = (const char*)apack + (size_t)mt * 1048576 + (size_t)tid * 16;

    const char* xpb = (const char*)xpad;
    const char* gb0;
    const char* gb1;
    {
        const int cellb = tid & 7;
        #pragma unroll
        for (int j = 0; j < 2; ++j) {
            const int brow = j * 64 + (tid >> 3);
            const int col  = nt * 128 + brow;
            const unsigned b = (unsigned)col / 626u;
            const int tc = col - (int)b * 626;
            const char* p = xpb + (size_t)b * (XPAD_STRIDE * 2) + (size_t)tc * 1024
                            + ((cellb ^ (brow & 7)) << 4);
            if (j == 0) gb0 = p; else gb1 = p;
        }
    }

    // ---- ds_read bases: byte = half*16384 + lrow*128 + ((chunk ^ (lrow&7))<<4)
    const int f7 = fr & 7;
    const unsigned aoff0 = (unsigned)((wm >> 1) * 16384 + ((wm & 1) * 64 + fr) * 128
                                      + ((kq ^ f7) << 4));
    const unsigned aoff1 = (unsigned)((wm >> 1) * 16384 + ((wm & 1) * 64 + fr) * 128
                                      + (((4 + kq) ^ f7) << 4));
    const unsigned boff0 = (unsigned)(32768 + (wn * 64 + fr) * 128 + ((kq ^ f7) << 4));
    const unsigned boff1 = (unsigned)(32768 + (wn * 64 + fr) * 128 + (((4 + kq) ^ f7) << 4));

    f32x4 acc[4][4];
    #pragma unroll
    for (int m = 0; m < 4; ++m)
        #pragma unroll
        for (int n = 0; n < 4; ++n)
            acc[m][n] = f32x4{0.f, 0.f, 0.f, 0.f};

    bf16x8 a00, a01, a10, a11, a20, a21, a30, a31;   // A cache for current tile

    // ---- prologue: stage tile 0 into buf 0, drain, barrier
    STGT(0, 0)
    VM0
    __builtin_amdgcn_s_barrier();
    __builtin_amdgcn_sched_barrier(0);

    // ---- main loop: tiles 0..29 (2 tiles/iter; buffers 0 / 49152)
    #pragma unroll 1
    for (int i = 0; i < 15; ++i) {
        PHA(0,     STGT(2 * i + 1, 49152))
        PHB(0,     VM0)
        PHA(49152, STGT(2 * i + 2, 0))
        PHB(49152, VM0)
    }
    // ---- tail: tiles 30, 31
    PHA(0,     STGT(31, 49152))
    PHB(0,     VM0)
    PHA(49152, )
    PHB(49152, )

    // ---- epilogue: C/D layout col = lane&15, row = kq*4 + j
    const size_t imag_base = (size_t)B_BATCH * NFREQ * T_OUT;
    #pragma unroll
    for (int n = 0; n < 4; ++n) {
        const int col = nt * 128 + wn * 64 + n * 16 + fr;
        if (col < NCOLS) {
            const unsigned b = (unsigned)col / 626u;
            const int tc = col - (int)b * 626;
            const size_t colbase = (size_t)b * NFREQ * T_OUT + (size_t)tc;
            #pragma unroll
            for (int m = 0; m < 4; ++m) {
                #pragma unroll
                for (int j = 0; j < 4; ++j) {
                    const int grow = mt * 256 + wm * 64 + m * 16 + kq * 4 + j;
                    if (grow < M_ROWS) {
                        const size_t off = (grow < NFREQ)
                            ? colbase + (size_t)grow * T_OUT
                            : imag_base + colbase + (size_t)(grow - NFREQ) * T_OUT;
                        out[off] = acc[m][n][j];
                    }
                }
            }
        }
    }
}

// ---------------- no-workspace fallback (round-1 structure) ----------------
__device__ __forceinline__ unsigned lds_off_fb(int row, int kbyte) {
    return (unsigned)(row * 128 + (kbyte ^ ((row & 7) << 4)));
}

__global__ __launch_bounds__(256) void stft_gemm_fb(
    const float* __restrict__ x,
    const float* __restrict__ wre,
    const float* __restrict__ wim,
    float* __restrict__ out)
{
    __shared__ __align__(16) unsigned char ldsA[128 * 128];
    __shared__ __align__(16) unsigned char ldsB[128 * 128];

    const int tid  = threadIdx.x;
    const int lane = tid & 63;
    const int wid  = tid >> 6;
    const int wmf  = wid >> 1;
    const int wnf  = wid & 1;

    const int bid = blockIdx.x;
    const int b   = bid / (17 * 5);
    const int rem = bid % (17 * 5);
    const int mt  = rem / 5;
    const int nt  = rem % 5;

    const int row0 = mt * 128;
    const int col0 = nt * 128;
    const float* xb = x + (size_t)b * XLEN;

    const int c4 = (tid & 15) * 4;
    const int r0 = tid >> 4;

    f32x4 acc[4][4];
    #pragma unroll
    for (int m = 0; m < 4; ++m)
        #pragma unroll
        for (int n = 0; n < 4; ++n)
            acc[m][n] = f32x4{0.f, 0.f, 0.f, 0.f};

    const int fr = lane & 15;
    const int kq = lane >> 4;

    for (int k0 = 0; k0 < NFFT; k0 += 64) {
        bf16x4 sa[8], sb[8];
        #pragma unroll
        for (int rr = 0; rr < 8; ++rr) {
            const int row  = rr * 16 + r0;
            const int grow = row0 + row;
            float4 v = make_float4(0.f, 0.f, 0.f, 0.f);
            if (grow < M_ROWS) {
                const float* wsrc = (grow < NFREQ)
                    ? (wre + (size_t)grow * NFFT)
                    : (wim + (size_t)(grow - NFREQ) * NFFT);
                v = *reinterpret_cast<const float4*>(wsrc + k0 + c4);
            }
            sa[rr].x = (__bf16)v.x; sa[rr].y = (__bf16)v.y;
            sa[rr].z = (__bf16)v.z; sa[rr].w = (__bf16)v.w;
        }
        #pragma unroll
        for (int rr = 0; rr < 8; ++rr) {
            const int trow = rr * 16 + r0;
            const int t    = col0 + trow;
            float4 v = make_float4(0.f, 0.f, 0.f, 0.f);
            if (t < T_OUT) {
                const int pos = t * HOP + k0 + c4 - PADW;
                if (pos >= 0 && pos <= XLEN - 4) {
                    v = *reinterpret_cast<const float4*>(xb + pos);
                } else {
                    float tmp[4];
                    #pragma unroll
                    for (int e = 0; e < 4; ++e) {
                        int p = pos + e;
                        p = (p < 0) ? -p : p;
                        p = (p >= XLEN) ? (2 * XLEN - 2 - p) : p;
                        tmp[e] = xb[p];
                    }
                    v = make_float4(tmp[0], tmp[1], tmp[2], tmp[3]);
                }
            }
            sb[rr].x = (__bf16)v.x; sb[rr].y = (__bf16)v.y;
            sb[rr].z = (__bf16)v.z; sb[rr].w = (__bf16)v.w;
        }
        __syncthreads();
        #pragma unroll
        for (int rr = 0; rr < 8; ++rr) {
            const int row = rr * 16 + r0;
            *reinterpret_cast<bf16x4*>(ldsA + lds_off_fb(row, c4 * 2)) = sa[rr];
            *reinterpret_cast<bf16x4*>(ldsB + lds_off_fb(row, c4 * 2)) = sb[rr];
        }
        __syncthreads();
        #pragma unroll
        for (int kk = 0; kk < 2; ++kk) {
            const int kbyte = kk * 64 + kq * 16;
            bf16x8 af[4], bfv[4];
            #pragma unroll
            for (int m = 0; m < 4; ++m)
                af[m] = *reinterpret_cast<const bf16x8*>(
                    ldsA + lds_off_fb(wmf * 64 + m * 16 + fr, kbyte));
            #pragma unroll
            for (int n = 0; n < 4; ++n)
                bfv[n] = *reinterpret_cast<const bf16x8*>(
                    ldsB + lds_off_fb(wnf * 64 + n * 16 + fr, kbyte));
            #pragma unroll
            for (int m = 0; m < 4; ++m)
                #pragma unroll
                for (int n = 0; n < 4; ++n)
                    acc[m][n] = MFMA16(af[m], bfv[n], acc[m][n], 0, 0, 0);
        }
    }

    const size_t imag_base = (size_t)B_BATCH * NFREQ * T_OUT;
    #pragma unroll
    for (int m = 0; m < 4; ++m) {
        #pragma unroll
        for (int n = 0; n < 4; ++n) {
            #pragma unroll
            for (int j = 0; j < 4; ++j) {
                const int grow = row0 + wmf * 64 + m * 16 + kq * 4 + j;
                const int gcol = col0 + wnf * 64 + n * 16 + fr;
                if (grow < M_ROWS && gcol < T_OUT) {
                    size_t off;
                    if (grow < NFREQ)
                        off = ((size_t)b * NFREQ + grow) * T_OUT + gcol;
                    else
                        off = imag_base + ((size_t)b * NFREQ + (grow - NFREQ)) * T_OUT + gcol;
                    out[off] = acc[m][n][j];
                }
            }
        }
    }
}

extern "C" void kernel_launch(void* const* d_in, const int* in_sizes, int n_in,
                              void* d_out, int out_size, void* d_ws, size_t ws_size,
                              hipStream_t stream) {
    const float* x   = (const float*)d_in[0];
    const float* wre = (const float*)d_in[1];
    const float* wim = (const float*)d_in[2];
    float* out = (float*)d_out;

    if (ws_size < WS_NEEDED) {
        stft_gemm_fb<<<dim3(B_BATCH * 17 * 5), 256, 0, stream>>>(x, wre, wim, out);
        return;
    }

    __bf16* apack = (__bf16*)d_ws;
    __bf16* xpad  = (__bf16*)((char*)d_ws + APACK_BYTES);

    prep_w<<<dim3(589824 / 256), 256, 0, stream>>>(wre, wim, apack);
    prep_x<<<dim3(((B_BATCH + 1) * (XPAD_STRIDE / 8) + 255) / 256), 256, 0, stream>>>(x, xpad);
    stft_gemm11<<<dim3(NBLK3), 512, 0, stream>>>(apack, xpad, out);
}